// Round 17
// baseline (26.870 us; speedup 1.0000x reference)
//
#include <hip/hip_runtime.h>
#include <math.h>

#define EPSN 1e-12f

typedef __attribute__((ext_vector_type(8))) __bf16 bf16x8;
typedef __attribute__((ext_vector_type(8))) short short8;
typedef __attribute__((ext_vector_type(4))) float floatx4;

static __device__ __forceinline__ unsigned short f2bf(float f) {
    return __builtin_bit_cast(unsigned short, (__bf16)f);
}

// ---------------------------------------------------------------------------
// Single-dispatch fused kernel. grid 256 (1 block/CU), 1024 threads (16 waves,
// 4 waves/SIMD). R16 datapath with work split 2x + wave specialization:
//   waves 0..7  : staging (R16-verified path verbatim) + compute rt=0
//   waves 8..15 : pure compute rt=1
//   phase-1: 64 row-tiles / 16 waves = 4 MFMA each (R15-verified scatter).
//   phase-2: wave w owns (rt=w>>3, m=(w&7)*16+cl); 4 MFMA/estep.
// LDS = 32KB xw + 2x32KB at + 2x8KB red = 112KB. Barriers: 4.
// ---------------------------------------------------------------------------
__global__ __launch_bounds__(1024, 4)
void gcn_one(const float* __restrict__ x, const float* __restrict__ A,
             const float* __restrict__ W, float* __restrict__ out) {
    __shared__ __align__(16) unsigned char xw[32768];     // [4e][32r][128n] swz
    __shared__ __align__(16) unsigned char at[2][32768];  // [128m][16oct] swz
    __shared__ float red[2][16][128];                     // ssq partials

    const int t   = threadIdx.x;
    const int bc0 = blockIdx.x * 8;
    const int w   = t >> 6;            // wave 0..15
    const int l   = t & 63;
    const int cl  = l & 15;
    const int lg  = l >> 4;
    const int rt  = w >> 3;            // phase-2 row-tile half
    const int mw  = (w & 7) * 16 + cl; // phase-2 m
    const bool stager = (t < 512);     // waves 0..7 stage A
    const int mq  = t & 31;            // A-stage m-quad (m = mq*4+i)
    const int ng  = (t >> 5) & 15;     // A-stage n-octet (n = ng*8+j)

    // ---- stagers: issue A[0] + A[1] loads up-front (fly under phase-1) ----
    float4 v4a[8], v4b[8];
    if (stager) {
        #pragma unroll
        for (int j = 0; j < 8; ++j)
            v4a[j] = *(const float4*)(A + (size_t)(ng * 8 + j) * 128 + mq * 4);
        #pragma unroll
        for (int j = 0; j < 8; ++j)
            v4b[j] = *(const float4*)(A + 16384 + (size_t)(ng * 8 + j) * 128 + mq * 4);
    }

    // ---- phase-1: XW via MFMA (R15-verified), 4 tiles per wave ----
    bf16x8 bW;
    {
        short8 z = {0, 0, 0, 0, 0, 0, 0, 0};
        bW = __builtin_bit_cast(bf16x8, z);
        if (lg < 2) {
            unsigned short hs[8] __attribute__((aligned(16)));
            #pragma unroll
            for (int j = 0; j < 8; ++j)
                hs[j] = f2bf(W[(cl >> 2) * 64 + (lg * 8 + j) * 4 + (cl & 3)]);
            bW = __builtin_bit_cast(bf16x8, *(const short8*)hs);
        }
    }
    #pragma unroll
    for (int ti = 0; ti < 4; ++ti) {
        int T = w * 4 + ti;                       // row-tile 0..63
        bf16x8 ax;
        { short8 z = {0, 0, 0, 0, 0, 0, 0, 0}; ax = __builtin_bit_cast(bf16x8, z); }
        if (lg < 2) {
            int R = T * 16 + cl;                  // local x-row 0..1023
            const float* xp = x + ((size_t)bc0 * 128 + R) * 16 + lg * 8;
            float4 a = *(const float4*)xp;
            float4 b = *(const float4*)(xp + 4);
            unsigned short hs[8] __attribute__((aligned(16)));
            hs[0] = f2bf(a.x); hs[1] = f2bf(a.y); hs[2] = f2bf(a.z); hs[3] = f2bf(a.w);
            hs[4] = f2bf(b.x); hs[5] = f2bf(b.y); hs[6] = f2bf(b.z); hs[7] = f2bf(b.w);
            ax = __builtin_bit_cast(bf16x8, *(const short8*)hs);
        }
        floatx4 d = {0.f, 0.f, 0.f, 0.f};
        d = __builtin_amdgcn_mfma_f32_16x16x32_bf16(ax, bW, d, 0, 0, 0);
        int eD = cl >> 2, oD = cl & 3;
        int bcl = T >> 3;
        int nb  = (T & 7) * 16 + lg * 4;
        int r   = bcl * 4 + oD;
        int base = (eD * 32 + r) << 8;
        int s    = (r & 7) << 4;
        #pragma unroll
        for (int q = 0; q < 4; ++q) {
            int off = (base + (nb + q) * 2) ^ s;
            *(unsigned short*)(xw + off) = f2bf(d[q]);
        }
    }

    // ---- at/red writer (R16-verified formulas; stagers only) ----
    auto stage_write = [&](int buf, const float4* v4) {
        floatx4 rs = {0.f, 0.f, 0.f, 0.f};
        #pragma unroll
        for (int i = 0; i < 4; ++i) {
            int m = mq * 4 + i;
            unsigned short hs[8] __attribute__((aligned(16)));
            #pragma unroll
            for (int j = 0; j < 8; ++j) {
                float vv = ((const float*)&v4[j])[i];
                rs[i] += vv * vv;
                hs[j] = f2bf(vv);
            }
            int slot = ng ^ (mq & 7);
            *(short8*)(at[buf] + ((m << 8) | (slot << 4))) = *(const short8*)hs;
        }
        *(float4*)&red[buf][ng][mq * 4] = *(const float4*)&rs;
    };

    if (stager) { stage_write(0, v4a); stage_write(1, v4b); }
    __syncthreads();

    // ---- compute step for edge e from buffer buf (one rt per wave) ----
    auto compute_e = [&](int e, int buf) {
        bf16x8 af[4];
        #pragma unroll
        for (int ks = 0; ks < 4; ++ks) {
            int row = rt * 16 + cl;
            int off = (((e * 32 + row) << 8) + (ks * 32 + lg * 8) * 2)
                      ^ ((row & 7) << 4);
            af[ks] = __builtin_bit_cast(bf16x8, *(const short8*)(xw + off));
        }
        bf16x8 bfr[4];
        #pragma unroll
        for (int ks = 0; ks < 4; ++ks) {
            int slot = (ks * 4 + lg) ^ ((mw >> 2) & 7);
            bfr[ks] = __builtin_bit_cast(bf16x8,
                *(const short8*)(at[buf] + ((mw << 8) | (slot << 4))));
        }
        floatx4 acc = {0.f, 0.f, 0.f, 0.f};
        #pragma unroll
        for (int ks = 0; ks < 4; ++ks)
            acc = __builtin_amdgcn_mfma_f32_16x16x32_bf16(af[ks], bfr[ks], acc, 0, 0, 0);
        float ssum = 0.f;
        #pragma unroll
        for (int g = 0; g < 16; ++g) ssum += red[buf][g][mw];
        float rn = 1.0f / fmaxf(sqrtf(ssum), EPSN);
        int bc = bc0 + rt * 4 + lg;
        int b = bc >> 4, c = bc & 15;
        float4 o4;
        o4.x = fmaxf(acc[0] * rn, 0.f);
        o4.y = fmaxf(acc[1] * rn, 0.f);
        o4.z = fmaxf(acc[2] * rn, 0.f);
        o4.w = fmaxf(acc[3] * rn, 0.f);
        ((float4*)out)[(size_t)(b * 64 + e * 16 + c) * 128 + mw] = o4;
    };

    // ---- pipelined e-loop: stagers overlap next-stage with compute ----
    if (stager) {
        #pragma unroll
        for (int j = 0; j < 8; ++j)
            v4a[j] = *(const float4*)(A + 2 * 16384 + (size_t)(ng * 8 + j) * 128 + mq * 4);
    }
    compute_e(0, 0);
    __syncthreads();          // all reads of at0/red0 done
    if (stager) {
        stage_write(0, v4a);  // at0 <- A[2], overlaps compute_e(1) of waves 8..15
        #pragma unroll
        for (int j = 0; j < 8; ++j)
            v4b[j] = *(const float4*)(A + 3 * 16384 + (size_t)(ng * 8 + j) * 128 + mq * 4);
    }
    compute_e(1, 1);
    __syncthreads();          // reads of at1 done AND at0<-A2 writes done
    if (stager) stage_write(1, v4b);   // at1 <- A[3], overlaps compute_e(2)
    compute_e(2, 0);
    __syncthreads();          // at1<-A3 writes done
    compute_e(3, 1);
}

extern "C" void kernel_launch(void* const* d_in, const int* in_sizes, int n_in,
                              void* d_out, int out_size, void* d_ws, size_t ws_size,
                              hipStream_t stream) {
    const float* x = (const float*)d_in[0];   // [128,16,128,16]
    const float* A = (const float*)d_in[1];   // [4,128,128]
    const float* W = (const float*)d_in[2];   // [4,16,4]
    float* out = (float*)d_out;               // [128,64,128,4]

    gcn_one<<<256, 1024, 0, stream>>>(x, A, W, out);
}

// Round 18
// 25.708 us; speedup vs baseline: 1.0452x; 1.0452x over previous
//
#include <hip/hip_runtime.h>
#include <math.h>

#define EPSN 1e-12f

typedef __attribute__((ext_vector_type(8))) __bf16 bf16x8;
typedef __attribute__((ext_vector_type(8))) short short8;
typedef __attribute__((ext_vector_type(4))) float floatx4;

static __device__ __forceinline__ unsigned short f2bf(float f) {
    return __builtin_bit_cast(unsigned short, (__bf16)f);
}

// ---------------------------------------------------------------------------
// Single-dispatch fused kernel. grid 512 = (m-half h) x (256 bc-groups of 8).
// 512 threads (8 waves), 72KB LDS -> 2 blocks/CU (inter-block overlap).
//   phase-1 (MFMA): XW -> xw LDS [4e][32r][128n] swz (R15-verified; dup x2).
//   A-stage: 256 stager threads, 8 dwordx4 each for 64m x 128n half-tile;
//            slot = ng ^ (mq&7); ssq partials -> red[buf][16][64].
//   phase-2 per e: wave w -> (rt=w&1, m=(w>>1)*16+cl); af from xw, bfr from
//            at[buf], 4 MFMA; rnorm*relu epilogue, coalesced float4 stores.
//   Double-buffered at/red, 4 barriers (R16-verified pipeline).
// ---------------------------------------------------------------------------
__global__ __launch_bounds__(512, 2)
void gcn_one(const float* __restrict__ x, const float* __restrict__ A,
             const float* __restrict__ W, float* __restrict__ out) {
    __shared__ __align__(16) unsigned char xw[32768];     // [4e][32r][128n] swz
    __shared__ __align__(16) unsigned char at[2][16384];  // [64m][16oct] swz
    __shared__ float red[2][16][64];                      // ssq partials

    const int t   = threadIdx.x;
    const int gid = blockIdx.x;
    const int h   = gid >> 8;            // m-half; g, g+256 same XCD (256%8==0)
    const int bc0 = (gid & 255) * 8;
    const int m0  = h * 64;

    const int w   = t >> 6;              // wave 0..7
    const int l   = t & 63;
    const int cl  = l & 15;
    const int lg  = l >> 4;
    const int rt  = w & 1;               // phase-2 r-half
    const int mwl = (w >> 1) * 16 + cl;  // phase-2 local m (0..63)
    const bool stager = (t < 256);
    const int mq  = t & 15;              // stage m-quad (local m = mq*4+i)
    const int ng  = (t >> 4) & 15;       // stage n-octet (n = ng*8+j)

    // ---- stagers: issue A[0] + A[1] half-tile loads up-front ----
    float4 v4a[8], v4b[8];
    if (stager) {
        #pragma unroll
        for (int j = 0; j < 8; ++j)
            v4a[j] = *(const float4*)(A + (size_t)(ng * 8 + j) * 128 + m0 + mq * 4);
        #pragma unroll
        for (int j = 0; j < 8; ++j)
            v4b[j] = *(const float4*)(A + 16384 + (size_t)(ng * 8 + j) * 128 + m0 + mq * 4);
    }

    // ---- phase-1: XW via MFMA (R15-verified, 8 tiles/wave) ----
    bf16x8 bW;
    {
        short8 z = {0, 0, 0, 0, 0, 0, 0, 0};
        bW = __builtin_bit_cast(bf16x8, z);
        if (lg < 2) {
            unsigned short hs[8] __attribute__((aligned(16)));
            #pragma unroll
            for (int j = 0; j < 8; ++j)
                hs[j] = f2bf(W[(cl >> 2) * 64 + (lg * 8 + j) * 4 + (cl & 3)]);
            bW = __builtin_bit_cast(bf16x8, *(const short8*)hs);
        }
    }
    #pragma unroll
    for (int ti = 0; ti < 8; ++ti) {
        int T = w * 8 + ti;                       // row-tile 0..63
        bf16x8 ax;
        { short8 z = {0, 0, 0, 0, 0, 0, 0, 0}; ax = __builtin_bit_cast(bf16x8, z); }
        if (lg < 2) {
            int R = T * 16 + cl;                  // local x-row 0..1023
            const float* xp = x + ((size_t)bc0 * 128 + R) * 16 + lg * 8;
            float4 a = *(const float4*)xp;
            float4 b = *(const float4*)(xp + 4);
            unsigned short hs[8] __attribute__((aligned(16)));
            hs[0] = f2bf(a.x); hs[1] = f2bf(a.y); hs[2] = f2bf(a.z); hs[3] = f2bf(a.w);
            hs[4] = f2bf(b.x); hs[5] = f2bf(b.y); hs[6] = f2bf(b.z); hs[7] = f2bf(b.w);
            ax = __builtin_bit_cast(bf16x8, *(const short8*)hs);
        }
        floatx4 d = {0.f, 0.f, 0.f, 0.f};
        d = __builtin_amdgcn_mfma_f32_16x16x32_bf16(ax, bW, d, 0, 0, 0);
        int eD = cl >> 2, oD = cl & 3;
        int bcl = T >> 3;
        int nb  = (T & 7) * 16 + lg * 4;
        int r   = bcl * 4 + oD;
        int base = (eD * 32 + r) << 8;
        int s    = (r & 7) << 4;
        #pragma unroll
        for (int q = 0; q < 4; ++q) {
            int off = (base + (nb + q) * 2) ^ s;
            *(unsigned short*)(xw + off) = f2bf(d[q]);
        }
    }

    // ---- at/red writer (stagers only; local m < 64) ----
    auto stage_write = [&](int buf, const float4* v4) {
        floatx4 rs = {0.f, 0.f, 0.f, 0.f};
        #pragma unroll
        for (int i = 0; i < 4; ++i) {
            int m = mq * 4 + i;
            unsigned short hs[8] __attribute__((aligned(16)));
            #pragma unroll
            for (int j = 0; j < 8; ++j) {
                float vv = ((const float*)&v4[j])[i];
                rs[i] += vv * vv;
                hs[j] = f2bf(vv);
            }
            int slot = ng ^ (mq & 7);
            *(short8*)(at[buf] + ((m << 8) | (slot << 4))) = *(const short8*)hs;
        }
        *(float4*)&red[buf][ng][mq * 4] = *(const float4*)&rs;
    };

    if (stager) { stage_write(0, v4a); stage_write(1, v4b); }
    __syncthreads();

    // ---- compute step for edge e from buffer buf ----
    auto compute_e = [&](int e, int buf) {
        bf16x8 af[4];
        #pragma unroll
        for (int ks = 0; ks < 4; ++ks) {
            int row = rt * 16 + cl;
            int off = (((e * 32 + row) << 8) + (ks * 32 + lg * 8) * 2)
                      ^ ((row & 7) << 4);
            af[ks] = __builtin_bit_cast(bf16x8, *(const short8*)(xw + off));
        }
        bf16x8 bfr[4];
        #pragma unroll
        for (int ks = 0; ks < 4; ++ks) {
            int slot = (ks * 4 + lg) ^ ((mwl >> 2) & 7);
            bfr[ks] = __builtin_bit_cast(bf16x8,
                *(const short8*)(at[buf] + ((mwl << 8) | (slot << 4))));
        }
        floatx4 acc = {0.f, 0.f, 0.f, 0.f};
        #pragma unroll
        for (int ks = 0; ks < 4; ++ks)
            acc = __builtin_amdgcn_mfma_f32_16x16x32_bf16(af[ks], bfr[ks], acc, 0, 0, 0);
        float ssum = 0.f;
        #pragma unroll
        for (int g = 0; g < 16; ++g) ssum += red[buf][g][mwl];
        float rn = 1.0f / fmaxf(sqrtf(ssum), EPSN);
        int bc = bc0 + rt * 4 + lg;
        int b = bc >> 4, c = bc & 15;
        float4 o4;
        o4.x = fmaxf(acc[0] * rn, 0.f);
        o4.y = fmaxf(acc[1] * rn, 0.f);
        o4.z = fmaxf(acc[2] * rn, 0.f);
        o4.w = fmaxf(acc[3] * rn, 0.f);
        ((float4*)out)[(size_t)(b * 64 + e * 16 + c) * 128 + m0 + mwl] = o4;
    };

    // ---- pipelined e-loop (R16-verified barrier structure) ----
    if (stager) {
        #pragma unroll
        for (int j = 0; j < 8; ++j)
            v4a[j] = *(const float4*)(A + 2 * 16384 + (size_t)(ng * 8 + j) * 128 + m0 + mq * 4);
    }
    compute_e(0, 0);
    __syncthreads();          // all reads of at0/red0 done
    if (stager) {
        stage_write(0, v4a);  // at0 <- A[2]
        #pragma unroll
        for (int j = 0; j < 8; ++j)
            v4b[j] = *(const float4*)(A + 3 * 16384 + (size_t)(ng * 8 + j) * 128 + m0 + mq * 4);
    }
    compute_e(1, 1);
    __syncthreads();          // reads of at1 done AND at0<-A2 writes done
    if (stager) stage_write(1, v4b);   // at1 <- A[3]
    compute_e(2, 0);
    __syncthreads();          // at1<-A3 writes done
    compute_e(3, 1);
}

extern "C" void kernel_launch(void* const* d_in, const int* in_sizes, int n_in,
                              void* d_out, int out_size, void* d_ws, size_t ws_size,
                              hipStream_t stream) {
    const float* x = (const float*)d_in[0];   // [128,16,128,16]
    const float* A = (const float*)d_in[1];   // [4,128,128]
    const float* W = (const float*)d_in[2];   // [4,16,4]
    float* out = (float*)d_out;               // [128,64,128,4]

    gcn_one<<<512, 512, 0, stream>>>(x, A, W, out);
}

// Round 19
// 18.511 us; speedup vs baseline: 1.4516x; 1.3888x over previous
//
#include <hip/hip_runtime.h>
#include <math.h>

#define EPSN 1e-12f

typedef __attribute__((ext_vector_type(8))) __bf16 bf16x8;
typedef __attribute__((ext_vector_type(8))) short short8;
typedef __attribute__((ext_vector_type(4))) float floatx4;

static __device__ __forceinline__ unsigned short f2bf(float f) {
    return __builtin_bit_cast(unsigned short, (__bf16)f);
}

// ---------------------------------------------------------------------------
// FINAL (best of series, R16): single-dispatch fused kernel.
// grid 256 (1 block/CU), 512 threads (8 waves).
// Double-buffered at/red: compute(e) overlaps stage(e+2). Barriers: 4.
// LDS = 32KB xw + 2x32KB at + 2x8KB red = 112KB.
//   phase-1 (MFMA): XW (M=1024, N=16=(e,o), K=16 zero-padded) -> xw LDS, swz.
//   A-stage: thread owns m-quad x n-octet, 8 dwordx4/estep;
//            slot = oct ^ ((m>>2)&7); ssq partials -> red.
//   phase-2 per e: af[2][4] from xw, bfr[4] from at[e&1], 8 MFMA;
//            rnorm*relu epilogue, coalesced float4 stores.
// ---------------------------------------------------------------------------
__global__ __launch_bounds__(512, 2)
void gcn_one(const float* __restrict__ x, const float* __restrict__ A,
             const float* __restrict__ W, float* __restrict__ out) {
    __shared__ __align__(16) unsigned char xw[32768];     // [4e][32r][128n] swz
    __shared__ __align__(16) unsigned char at[2][32768];  // [128m][16oct] swz
    __shared__ float red[2][16][128];                     // ssq partials

    const int t   = threadIdx.x;
    const int bc0 = blockIdx.x * 8;
    const int w   = t >> 6;            // wave 0..7
    const int l   = t & 63;
    const int cl  = l & 15;
    const int lg  = l >> 4;
    const int mw  = w * 16 + cl;       // phase-2 m
    const int mq  = t & 31;            // A-stage m-quad (m = mq*4+i)
    const int ng  = t >> 5;            // A-stage n-octet (n = ng*8+j)

    // ---- issue A[0] + A[1] loads up-front (fly under phase-1) ----
    float4 v4a[8], v4b[8];
    #pragma unroll
    for (int j = 0; j < 8; ++j)
        v4a[j] = *(const float4*)(A + (size_t)(ng * 8 + j) * 128 + mq * 4);
    #pragma unroll
    for (int j = 0; j < 8; ++j)
        v4b[j] = *(const float4*)(A + 16384 + (size_t)(ng * 8 + j) * 128 + mq * 4);

    // ---- phase-1: XW via MFMA (R15-verified) ----
    bf16x8 bW;
    {
        short8 z = {0, 0, 0, 0, 0, 0, 0, 0};
        bW = __builtin_bit_cast(bf16x8, z);
        if (lg < 2) {
            unsigned short hs[8] __attribute__((aligned(16)));
            #pragma unroll
            for (int j = 0; j < 8; ++j)
                hs[j] = f2bf(W[(cl >> 2) * 64 + (lg * 8 + j) * 4 + (cl & 3)]);
            bW = __builtin_bit_cast(bf16x8, *(const short8*)hs);
        }
    }
    #pragma unroll
    for (int ti = 0; ti < 8; ++ti) {
        int T = w * 8 + ti;                       // row-tile 0..63
        bf16x8 ax;
        { short8 z = {0, 0, 0, 0, 0, 0, 0, 0}; ax = __builtin_bit_cast(bf16x8, z); }
        if (lg < 2) {
            int R = T * 16 + cl;                  // local x-row 0..1023
            const float* xp = x + ((size_t)bc0 * 128 + R) * 16 + lg * 8;
            float4 a = *(const float4*)xp;
            float4 b = *(const float4*)(xp + 4);
            unsigned short hs[8] __attribute__((aligned(16)));
            hs[0] = f2bf(a.x); hs[1] = f2bf(a.y); hs[2] = f2bf(a.z); hs[3] = f2bf(a.w);
            hs[4] = f2bf(b.x); hs[5] = f2bf(b.y); hs[6] = f2bf(b.z); hs[7] = f2bf(b.w);
            ax = __builtin_bit_cast(bf16x8, *(const short8*)hs);
        }
        floatx4 d = {0.f, 0.f, 0.f, 0.f};
        d = __builtin_amdgcn_mfma_f32_16x16x32_bf16(ax, bW, d, 0, 0, 0);
        int eD = cl >> 2, oD = cl & 3;
        int bcl = T >> 3;
        int nb  = (T & 7) * 16 + lg * 4;
        int r   = bcl * 4 + oD;
        int base = (eD * 32 + r) << 8;
        int s    = (r & 7) << 4;
        #pragma unroll
        for (int q = 0; q < 4; ++q) {
            int off = (base + (nb + q) * 2) ^ s;
            *(unsigned short*)(xw + off) = f2bf(d[q]);
        }
    }

    // ---- at/red writer (R15-verified formulas) ----
    auto stage_write = [&](int buf, const float4* v4) {
        floatx4 rs = {0.f, 0.f, 0.f, 0.f};
        #pragma unroll
        for (int i = 0; i < 4; ++i) {
            int m = mq * 4 + i;
            unsigned short hs[8] __attribute__((aligned(16)));
            #pragma unroll
            for (int j = 0; j < 8; ++j) {
                float vv = ((const float*)&v4[j])[i];
                rs[i] += vv * vv;
                hs[j] = f2bf(vv);
            }
            int slot = ng ^ (mq & 7);
            *(short8*)(at[buf] + ((m << 8) | (slot << 4))) = *(const short8*)hs;
        }
        *(float4*)&red[buf][ng][mq * 4] = *(const float4*)&rs;
    };

    stage_write(0, v4a);
    stage_write(1, v4b);
    __syncthreads();

    // ---- compute step for edge e from buffer buf ----
    auto compute_e = [&](int e, int buf) {
        bf16x8 af[2][4];
        #pragma unroll
        for (int rt = 0; rt < 2; ++rt)
            #pragma unroll
            for (int ks = 0; ks < 4; ++ks) {
                int row = rt * 16 + cl;
                int off = (((e * 32 + row) << 8) + (ks * 32 + lg * 8) * 2)
                          ^ ((row & 7) << 4);
                af[rt][ks] = __builtin_bit_cast(bf16x8, *(const short8*)(xw + off));
            }
        bf16x8 bfr[4];
        #pragma unroll
        for (int ks = 0; ks < 4; ++ks) {
            int slot = (ks * 4 + lg) ^ ((mw >> 2) & 7);
            bfr[ks] = __builtin_bit_cast(bf16x8,
                *(const short8*)(at[buf] + ((mw << 8) | (slot << 4))));
        }
        floatx4 acc0 = {0.f, 0.f, 0.f, 0.f};
        floatx4 acc1 = {0.f, 0.f, 0.f, 0.f};
        #pragma unroll
        for (int ks = 0; ks < 4; ++ks) {
            acc0 = __builtin_amdgcn_mfma_f32_16x16x32_bf16(af[0][ks], bfr[ks], acc0, 0, 0, 0);
            acc1 = __builtin_amdgcn_mfma_f32_16x16x32_bf16(af[1][ks], bfr[ks], acc1, 0, 0, 0);
        }
        float ssum = 0.f;
        #pragma unroll
        for (int g = 0; g < 16; ++g) ssum += red[buf][g][mw];
        float rn = 1.0f / fmaxf(sqrtf(ssum), EPSN);
        #pragma unroll
        for (int rt = 0; rt < 2; ++rt) {
            floatx4 a = rt ? acc1 : acc0;
            int bc = bc0 + rt * 4 + lg;
            int b = bc >> 4, c = bc & 15;
            float4 o4;
            o4.x = fmaxf(a[0] * rn, 0.f);
            o4.y = fmaxf(a[1] * rn, 0.f);
            o4.z = fmaxf(a[2] * rn, 0.f);
            o4.w = fmaxf(a[3] * rn, 0.f);
            ((float4*)out)[(size_t)(b * 64 + e * 16 + c) * 128 + mw] = o4;
        }
    };

    // ---- pipelined e-loop: compute(e) overlaps stage(e+2) ----
    #pragma unroll
    for (int j = 0; j < 8; ++j)
        v4a[j] = *(const float4*)(A + 2 * 16384 + (size_t)(ng * 8 + j) * 128 + mq * 4);
    compute_e(0, 0);
    __syncthreads();          // all reads of at0/red0 done
    stage_write(0, v4a);      // at0 <- A[2]

    #pragma unroll
    for (int j = 0; j < 8; ++j)
        v4b[j] = *(const float4*)(A + 3 * 16384 + (size_t)(ng * 8 + j) * 128 + mq * 4);
    compute_e(1, 1);
    __syncthreads();          // reads of at1 done AND at0<-A2 writes done
    stage_write(1, v4b);      // at1 <- A[3]

    compute_e(2, 0);
    __syncthreads();          // at1<-A3 writes done
    compute_e(3, 1);
}

extern "C" void kernel_launch(void* const* d_in, const int* in_sizes, int n_in,
                              void* d_out, int out_size, void* d_ws, size_t ws_size,
                              hipStream_t stream) {
    const float* x = (const float*)d_in[0];   // [128,16,128,16]
    const float* A = (const float*)d_in[1];   // [4,128,128]
    const float* W = (const float*)d_in[2];   // [4,16,4]
    float* out = (float*)d_out;               // [128,64,128,4]

    gcn_one<<<256, 512, 0, stream>>>(x, A, W, out);
}